// Round 2
// baseline (142.251 us; speedup 1.0000x reference)
//
#include <hip/hip_runtime.h>
#include <math.h>

// Problem constants (from reference): K=32 components, D=16 dims,
// component stride = 1 + D + D(D+1)/2 = 153 floats, row = 32*153 = 4896 floats.
#define KCOMP   32
#define DDIM    16
#define CSTRIDE 153
#define ROWF    (KCOMP * CSTRIDE)     // 4896 floats per batch row
#define ROWB    (ROWF * 4)            // 19584 bytes per batch row
#define TROWS   2                     // batch rows per wave (one per half-wave)
#define TILE_F  (TROWS * ROWF)        // 9792 floats per tile
#define TILE_B  (TROWS * ROWB)        // 39168 bytes staged per buffer
#define NLD16   (TILE_B / 1024)       // 38 full 1KB global_load_lds
// remainder: 256 B = 64 lanes x 4 B (exact)
#define LOADS_PER_TILE (NLD16 + 1)    // 39 -> vmcnt count for one tile in flight
#define GRID    512                   // 2 persistent 1-wave blocks per CU

// async global->LDS, linear layout (wave-uniform LDS base + lane*size)
#define GLOAD_LDS16(gsrc, ldst)                                                \
    __builtin_amdgcn_global_load_lds(                                          \
        (const __attribute__((address_space(1))) void*)(gsrc),                 \
        (__attribute__((address_space(3))) void*)(ldst), 16, 0, 0)
#define GLOAD_LDS4(gsrc, ldst)                                                 \
    __builtin_amdgcn_global_load_lds(                                          \
        (const __attribute__((address_space(1))) void*)(gsrc),                 \
        (__attribute__((address_space(3))) void*)(ldst), 4, 0, 0)

__global__ __launch_bounds__(64)
void mdn_logp_kernel(const float* __restrict__ p,
                     const float* __restrict__ y,
                     float* __restrict__ out,
                     int ntiles)
{
    // double-buffered staging: 2 x 39168 B = 78336 B -> 2 blocks/CU
    __shared__ float lds[2 * TILE_F];

    const int lane   = threadIdx.x & 63;
    const int stride = gridDim.x;

    // ---- stage one tile (2 batch rows) into LDS buffer, fully coalesced ----
    auto stage = [&](int buf, long tile) {
        const char* g = (const char*)p + tile * (long)TILE_B;
        char* l = (char*)&lds[buf * TILE_F];
        #pragma unroll
        for (int c = 0; c < NLD16; ++c)
            GLOAD_LDS16(g + c * 1024 + lane * 16, l + c * 1024);
        GLOAD_LDS4(g + NLD16 * 1024 + lane * 4, l + NLD16 * 1024);
    };

    const long t0 = blockIdx.x;
    if (t0 < ntiles) stage(0, t0);
    int cur = 0;

    for (long t = t0; t < ntiles; t += stride) {
        const long tn = t + stride;
        const bool pf = (tn < ntiles);
        if (pf) {
            stage(cur ^ 1, tn);
            // wait for current tile only; keep next tile's 39 loads in flight
            asm volatile("s_waitcnt vmcnt(39)" ::: "memory");
        } else {
            asm volatile("s_waitcnt vmcnt(0)" ::: "memory");
        }
        // single wave per block: no barrier needed

        // ---- half-wave r owns row 2t+r, lane k owns component k ----
        const int  r   = lane >> 5;
        const int  k   = lane & 31;
        const long row = t * TROWS + r;

        const float* comp = &lds[cur * TILE_F + r * ROWF + k * CSTRIDE]; // word-stride 153 (odd): conflict-free
        const float* yr   = y + row * DDIM;

        const float pi_v = comp[0];

        // diff = y - loc  (y is 16B-aligned: vectorize)
        float diff[DDIM];
        {
            const float4* y4 = (const float4*)yr;
            float4 v0 = y4[0], v1 = y4[1], v2 = y4[2], v3 = y4[3];
            float yv[DDIM] = { v0.x, v0.y, v0.z, v0.w,  v1.x, v1.y, v1.z, v1.w,
                               v2.x, v2.y, v2.z, v2.w,  v3.x, v3.y, v3.z, v3.w };
            #pragma unroll
            for (int d = 0; d < DDIM; ++d) diff[d] = yv[d] - comp[1 + d];
        }

        // ---- streaming forward substitution: z = L^-1 diff ----
        // st_par row-major over tril(i,j): idx(i,j) = i(i+1)/2 + j
        const float* st = comp + 1 + DDIM;
        float z[DDIM];
        float sumsq = 0.0f, hld = 0.0f;
        int idx = 0;
        #pragma unroll
        for (int i = 0; i < DDIM; ++i) {
            float acc = diff[i];
            #pragma unroll
            for (int j = 0; j < i; ++j)
                acc = fmaf(-st[idx + j], z[j], acc);
            float dr = fmaxf(st[idx + i], -15.0f);
            // stable softplus: max(x,0) + log1p(exp(-|x|))
            float sp = fmaxf(dr, 0.0f) + log1pf(expf(-fabsf(dr)));
            float zi = acc / sp;
            z[i] = zi;
            sumsq = fmaf(zi, zi, sumsq);
            hld += logf(sp);
            idx += i + 1;
        }

        const float LOG_2PI = 1.8378770664093453f;
        const float clp = -0.5f * (sumsq + (float)DDIM * LOG_2PI) - hld;
        const float lw  = fmaxf(pi_v, -15.0f);
        const float a   = lw + clp;

        // ---- logsumexp over 32 components (within each half-wave) ----
        // out = LSE(lw + clp) - LSE(lw)  (== LSE(log_softmax(pi) + clp))
        float m_a = a, m_w = lw;
        #pragma unroll
        for (int s = 16; s > 0; s >>= 1) {
            m_a = fmaxf(m_a, __shfl_xor(m_a, s, 32));
            m_w = fmaxf(m_w, __shfl_xor(m_w, s, 32));
        }
        float e_a = expf(a  - m_a);
        float e_w = expf(lw - m_w);
        #pragma unroll
        for (int s = 16; s > 0; s >>= 1) {
            e_a += __shfl_xor(e_a, s, 32);
            e_w += __shfl_xor(e_w, s, 32);
        }

        if (k == 0)
            out[row] = (m_a + logf(e_a)) - (m_w + logf(e_w));

        cur ^= 1;
    }
}

extern "C" void kernel_launch(void* const* d_in, const int* in_sizes, int n_in,
                              void* d_out, int out_size, void* d_ws, size_t ws_size,
                              hipStream_t stream) {
    (void)n_in; (void)d_ws; (void)ws_size;
    const float* p = (const float*)d_in[0];
    const float* y = (const float*)d_in[1];
    float* out = (float*)d_out;

    const int B      = out_size;         // 16384 batch rows
    const int ntiles = B / TROWS;        // 8192 tiles of 2 rows
    const int grid   = (ntiles < GRID) ? ntiles : GRID;
    mdn_logp_kernel<<<grid, 64, 0, stream>>>(p, y, out, ntiles);
}

// Round 3
// 112.395 us; speedup vs baseline: 1.2656x; 1.2656x over previous
//
#include <hip/hip_runtime.h>
#include <math.h>

// Problem constants: K=32 components, D=16 dims,
// component stride = 1 + D + D(D+1)/2 = 153 floats; p-row = 32*153 = 4896 floats.
#define KCOMP   32
#define DDIM    16
#define CSTRIDE 153
#define ROWF    4896                  // floats per p-row
#define ROWB    19584                 // bytes per p-row
#define NMAIN   19                    // 19 full 1KB global_load_lds per row
// LDS unit layout (words): [0..4864) main, [4864..4928) tail (valid to 4895),
// [4928..4992) y row (valid 16 words). Unit = 4992 words = 19968 B.
#define UNIT_W  4992
#define TAILB   (NMAIN * 1024)        // byte offset 19456
#define Y_W     4928                  // word offset of staged y row
#define LOADS   21                    // vmem ops per tile (19 + tail + y)
#define NUNITS  1024                  // persistent 1-wave blocks (4/CU)

// async global->LDS: LDS dest is wave-uniform base + lane*size (linear);
// global source IS per-lane (we exploit that to clamp tail/y addresses).
#define GL16(gsrc, ldst)                                                       \
    __builtin_amdgcn_global_load_lds(                                          \
        (const __attribute__((address_space(1))) void*)(gsrc),                 \
        (__attribute__((address_space(3))) void*)(ldst), 16, 0, 0)
#define GL4(gsrc, ldst)                                                        \
    __builtin_amdgcn_global_load_lds(                                          \
        (const __attribute__((address_space(1))) void*)(gsrc),                 \
        (__attribute__((address_space(3))) void*)(ldst), 4, 0, 0)

__global__ __launch_bounds__(64)
void mdn_logp_kernel(const float* __restrict__ p,
                     const float* __restrict__ y,
                     float* __restrict__ out,
                     int nrows)
{
    __shared__ float lds[2 * UNIT_W];   // 39936 B -> 4 blocks/CU (1 wave each)
    const int lane = threadIdx.x & 63;

    // stage one batch row (p-row + its y-row) into LDS buffer `buf`
    auto stage = [&](int buf, int row) {
        const char* g = (const char*)p + (long)row * ROWB;
        char* l = (char*)&lds[buf * UNIT_W];
        #pragma unroll
        for (int c = 0; c < NMAIN; ++c)
            GL16(g + c * 1024 + lane * 16, l + c * 1024);
        // tail: 128 valid bytes; lanes 32-63 duplicate lanes 0-31 (src clamped,
        // they write LDS words 4896..4927 which are never read)
        GL4(g + TAILB + (lane & 31) * 4, l + TAILB);
        // y row: 64 valid bytes; all lanes' sources clamped inside the row
        GL4((const char*)y + (long)row * (DDIM * 4) + (lane & 15) * 4,
            l + Y_W * 4);
    };

    const int r0 = blockIdx.x;
    if (r0 < nrows) stage(0, r0);
    int cur = 0;

    for (int r = r0; r < nrows; r += NUNITS) {
        const int rn = r + NUNITS;
        if (rn < nrows) {
            stage(cur ^ 1, rn);
            // wait for current tile (oldest 21+store); keep next tile in flight
            asm volatile("s_waitcnt vmcnt(21)" ::: "memory");
        } else {
            asm volatile("s_waitcnt vmcnt(0)" ::: "memory");
        }
        // single wave per block: no barrier needed

        // all 64 lanes compute; halves duplicate (k = lane&31) -> LDS broadcast
        const int    k    = lane & 31;
        const float* ub   = &lds[cur * UNIT_W];
        const float* comp = ub + k * CSTRIDE;   // word-stride 153 (odd): conflict-free
        const float* yv   = ub + Y_W;           // same addr all lanes: broadcast

        const float pi_v = comp[0];

        float diff[DDIM];
        #pragma unroll
        for (int d = 0; d < DDIM; ++d) diff[d] = yv[d] - comp[1 + d];

        // streaming forward substitution: z = L^-1 diff
        // st_par row-major over tril(i,j): idx(i,j) = i(i+1)/2 + j
        const float* st = comp + 1 + DDIM;
        float z[DDIM];
        float sumsq = 0.0f, hld = 0.0f;
        int idx = 0;
        #pragma unroll
        for (int i = 0; i < DDIM; ++i) {
            float acc = diff[i];
            #pragma unroll
            for (int j = 0; j < i; ++j)
                acc = fmaf(-st[idx + j], z[j], acc);
            float dr = fmaxf(st[idx + i], -15.0f);
            // stable softplus: max(x,0) + log1p(exp(-|x|))
            float sp = fmaxf(dr, 0.0f) + log1pf(expf(-fabsf(dr)));
            float zi = acc / sp;
            z[i] = zi;
            sumsq = fmaf(zi, zi, sumsq);
            hld += logf(sp);
            idx += i + 1;
        }

        const float LOG_2PI = 1.8378770664093453f;
        const float clp = -0.5f * (sumsq + (float)DDIM * LOG_2PI) - hld;
        const float lw  = fmaxf(pi_v, -15.0f);
        const float a   = lw + clp;

        // logsumexp over 32 components (within each half-wave)
        // out = LSE(lw + clp) - LSE(lw)  (== LSE(log_softmax(pi) + clp))
        float m_a = a, m_w = lw;
        #pragma unroll
        for (int s = 16; s > 0; s >>= 1) {
            m_a = fmaxf(m_a, __shfl_xor(m_a, s, 32));
            m_w = fmaxf(m_w, __shfl_xor(m_w, s, 32));
        }
        float e_a = expf(a  - m_a);
        float e_w = expf(lw - m_w);
        #pragma unroll
        for (int s = 16; s > 0; s >>= 1) {
            e_a += __shfl_xor(e_a, s, 32);
            e_w += __shfl_xor(e_w, s, 32);
        }

        if (lane == 0)
            out[r] = (m_a + logf(e_a)) - (m_w + logf(e_w));

        cur ^= 1;
    }
}

extern "C" void kernel_launch(void* const* d_in, const int* in_sizes, int n_in,
                              void* d_out, int out_size, void* d_ws, size_t ws_size,
                              hipStream_t stream) {
    (void)n_in; (void)d_ws; (void)ws_size;
    const float* p = (const float*)d_in[0];
    const float* y = (const float*)d_in[1];
    float* out = (float*)d_out;

    const int nrows = out_size;                       // 16384 batch rows
    const int grid  = (nrows < NUNITS) ? nrows : NUNITS;  // 1024 persistent waves
    mdn_logp_kernel<<<grid, 64, 0, stream>>>(p, y, out, nrows);
}